// Round 10
// baseline (61.972 us; speedup 1.0000x reference)
//
#include <hip/hip_runtime.h>
#include <hip/hip_bf16.h>

#define NROWS 4096
#define DIM   1024           // K elements; 1024 B/row in fp8
#define BTM   256            // tile rows per block
#define BTN   128            // tile cols per block
#define BK    64             // K-step (64 B in fp8)
#define NKT   (DIM / BK)     // 16 K-steps
#define TEMP_INV 10.0f
#define INV_S2 0.00390625f   // 1/256 (fp8 stored as 16*x)

typedef float f32x4 __attribute__((ext_vector_type(4)));
typedef long  fp8x8;         // 8 x e4m3 in 2 VGPRs

__device__ __forceinline__ void gload16(const void* g, void* l) {
    __builtin_amdgcn_global_load_lds(
        (const __attribute__((address_space(1))) void*)g,
        (__attribute__((address_space(3))) void*)l, 16, 0, 0);
}

// Row-normalize fp32 -> fp8 e4m3 scaled by 16; zeroes partial accumulators.
__global__ __launch_bounds__(256) void normalize_k(const float* __restrict__ pred,
                                                   unsigned char* __restrict__ xn,
                                                   float* __restrict__ posw,
                                                   float* __restrict__ denw) {
    const int row = blockIdx.x;
    const int tid = threadIdx.x;
    const float4 v = reinterpret_cast<const float4*>(pred + (size_t)row * DIM)[tid];
    float ss = v.x * v.x + v.y * v.y + v.z * v.z + v.w * v.w;
    #pragma unroll
    for (int off = 32; off; off >>= 1) ss += __shfl_xor(ss, off, 64);
    __shared__ float red[4];
    if ((tid & 63) == 0) red[tid >> 6] = ss;
    __syncthreads();
    const float tot = red[0] + red[1] + red[2] + red[3];
    const float scale = 16.0f / fmaxf(sqrtf(tot), 1e-8f);
    int pk = __builtin_amdgcn_cvt_pk_fp8_f32(v.x * scale, v.y * scale, 0, false);
    pk     = __builtin_amdgcn_cvt_pk_fp8_f32(v.z * scale, v.w * scale, pk, true);
    reinterpret_cast<int*>(xn)[row * (DIM / 4) + tid] = pk;
    if (tid == 0) { posw[row] = 0.0f; denw[row] = 0.0f; }
}

#define BAR asm volatile("s_barrier" ::: "memory")

// Fused Gram-GEMM + contrastive epilogue.  256x128 fp8 tile, grid 16x32 =
// 512 blocks = 2 blocks/CU -> 16 waves/CU ingesting (staging scales with
// issuing waves: R4/R8/R9 at 8 waves = 21-25 GB/s/CU; m97-structure at 16
// waves = ~53).  Depth-3 counted pipeline: stage(kt+2) issued after the
// step's single barrier; vmcnt(3) waits only for tile kt (3 loads/thread).
// WAR ledger: slot (kt+2)%3 holds tile kt-1, whose ds_reads completed
// (data-dep before MFMA) before every wave's BAR(kt), which precedes any
// stage issue of step kt.  RAW: each wave's own vmcnt(3) precedes BAR.
__global__ __launch_bounds__(512, 4) void fused_gram(
        const unsigned char* __restrict__ xn, const int* __restrict__ tgt,
        float* __restrict__ posw, float* __restrict__ denw) {
    __shared__ unsigned char As[3][BTM * BK];   // 3 x 16 KB
    __shared__ unsigned char Bs[3][BTN * BK];   // 3 x  8 KB  (72 KB total)

    const int bi = blockIdx.x >> 5;    // 0..15
    const int bj = blockIdx.x & 31;    // 0..31 (consecutive ids share A-panel)
    const int rowbase = bi * BTM;
    const int colbase = bj * BTN;

    const int tid = threadIdx.x;
    const int w   = tid >> 6;
    const int l   = tid & 63;
    const int wr  = w >> 2;      // 0..1  (row half: 128 rows)
    const int wc  = w & 3;       // 0..3  (col quarter: 32 cols)
    const int l15 = l & 15;
    const int kgl = l >> 4;      // 0..3
    const int gk  = kgl >> 1;    // granule-half selector
    const int hb  = (kgl & 1) * 8;

    const unsigned char* arow = xn + (size_t)rowbase * DIM;
    const unsigned char* bcol = xn + (size_t)colbase * DIM;

    // Stage tile kt into slot s.  Rows are 64 B = 4 granules of 16 B; bank
    // swizzle kg ^= r&3 pre-applied on the global source (rule 21).
#define STAGE_A(kt_, s_)                                                       \
    do {                                                                       \
        _Pragma("unroll")                                                      \
        for (int c = 0; c < 2; ++c) {                                          \
            const int p  = c * 512 + tid;                                      \
            const int r  = p >> 2;                                             \
            const int kg = (p & 3) ^ (r & 3);                                  \
            gload16(arow + (size_t)r * DIM + (kt_) * BK + kg * 16,             \
                    &As[s_][p * 16]);                                          \
        }                                                                      \
    } while (0)
#define STAGE_B(kt_, s_)                                                       \
    do {                                                                       \
        const int p  = tid;                                                    \
        const int r  = p >> 2;                                                 \
        const int kg = (p & 3) ^ (r & 3);                                      \
        gload16(bcol + (size_t)r * DIM + (kt_) * BK + kg * 16,                 \
                &Bs[s_][p * 16]);                                              \
    } while (0)

    f32x4 acc[8][2];
    #pragma unroll
    for (int i = 0; i < 8; ++i)
        #pragma unroll
        for (int j = 0; j < 2; ++j)
            acc[i][j] = (f32x4){0.f, 0.f, 0.f, 0.f};

    // Prologue: tiles 0 -> slot 0, 1 -> slot 1 (3 loads/thread each).
    STAGE_A(0, 0); STAGE_B(0, 0);
    STAGE_A(1, 1); STAGE_B(1, 1);

    int sc = 0;   // compute slot (kt % 3)
    for (int kt = 0; kt < NKT; ++kt) {
        if (kt == NKT - 1) asm volatile("s_waitcnt vmcnt(0)" ::: "memory");
        else               asm volatile("s_waitcnt vmcnt(3)" ::: "memory");
        BAR;
        if (kt + 2 < NKT) {
            const int ss = sc == 0 ? 2 : sc - 1;   // (kt+2) % 3
            STAGE_A(kt + 2, ss); STAGE_B(kt + 2, ss);
        }

        const unsigned char* as = &As[sc][0];
        const unsigned char* bs = &Bs[sc][0];
        #pragma unroll
        for (int ks = 0; ks < 2; ++ks) {
            const int xg = ((ks * 2 + gk) ^ (l15 & 3)) * 16 + hb;
            fp8x8 a[8], b[2];
            #pragma unroll
            for (int fi = 0; fi < 8; ++fi)
                a[fi] = *reinterpret_cast<const fp8x8*>(
                    &as[(wr * 128 + fi * 16 + l15) * 64 + xg]);
            #pragma unroll
            for (int fj = 0; fj < 2; ++fj)
                b[fj] = *reinterpret_cast<const fp8x8*>(
                    &bs[(wc * 32 + fj * 16 + l15) * 64 + xg]);
            __builtin_amdgcn_s_setprio(1);
            #pragma unroll
            for (int fi = 0; fi < 8; ++fi)
                #pragma unroll
                for (int fj = 0; fj < 2; ++fj)
                    acc[fi][fj] = __builtin_amdgcn_mfma_f32_16x16x32_fp8_fp8(
                        a[fi], b[fj], acc[fi][fj], 0, 0, 0);
            __builtin_amdgcn_s_setprio(0);
        }
        sc = sc == 2 ? 0 : sc + 1;
    }
#undef STAGE_A
#undef STAGE_B

    // Fused epilogue (column-side only; full grid covers both (i,j),(j,i)).
    // C/D layout: col = lane&15, row = (lane>>4)*4 + q.  p = acc/256.
    int jc[2], tj[2];
    #pragma unroll
    for (int fj = 0; fj < 2; ++fj) {
        jc[fj] = colbase + wc * 32 + fj * 16 + l15;
        tj[fj] = tgt[jc[fj]];
    }
    float denc[2] = {0.f, 0.f};
    float posc[2] = {0.f, 0.f};

    #pragma unroll
    for (int fi = 0; fi < 8; ++fi) {
        const int ribase = rowbase + wr * 128 + fi * 16 + (l >> 4) * 4;
        const int4 tiv = *reinterpret_cast<const int4*>(&tgt[ribase]);
        const int tia[4] = {tiv.x, tiv.y, tiv.z, tiv.w};
        #pragma unroll
        for (int q = 0; q < 4; ++q) {
            const int gi = ribase + q;
            const int ti = tia[q];
            #pragma unroll
            for (int fj = 0; fj < 2; ++fj) {
                const float s  = acc[fi][fj][q] * INV_S2;
                const float pc = fmaxf(s, 1e-10f);
                const float e  = __expf(TEMP_INV * pc);
                if (ti != tj[fj]) {
                    denc[fj] += e;
                } else if (gi != jc[fj]) {
                    posc[fj] += pc;
                }
            }
        }
    }

    // Lanes sharing a column differ in bits 4-5.
    #pragma unroll
    for (int fj = 0; fj < 2; ++fj) {
        #pragma unroll
        for (int off = 16; off < 64; off <<= 1) {
            denc[fj] += __shfl_xor(denc[fj], off, 64);
            posc[fj] += __shfl_xor(posc[fj], off, 64);
        }
        if (l < 16) {
            atomicAdd(&denw[jc[fj]], denc[fj]);
            atomicAdd(&posw[jc[fj]], posc[fj]);
        }
    }
}

// Single-block finalize: LDS class histogram + per-column loss + direct store.
__global__ __launch_bounds__(1024) void finalize_k(const float* __restrict__ posw,
                                                   const float* __restrict__ denw,
                                                   const int* __restrict__ tgt,
                                                   float* __restrict__ out) {
    __shared__ int hist[128];
    __shared__ float red[16];
    const int tid = threadIdx.x;
    if (tid < 128) hist[tid] = 0;
    __syncthreads();
    const int4 t4 = reinterpret_cast<const int4*>(tgt)[tid];   // 4 targets/thread
    atomicAdd(&hist[t4.x], 1);
    atomicAdd(&hist[t4.y], 1);
    atomicAdd(&hist[t4.z], 1);
    atomicAdd(&hist[t4.w], 1);
    __syncthreads();
    const int ta[4] = {t4.x, t4.y, t4.z, t4.w};
    float v = 0.0f;
    #pragma unroll
    for (int q = 0; q < 4; ++q) {
        const int j = tid * 4 + q;
        const float d = fmaxf(denw[j], 1e-10f);
        const float c = (float)(hist[ta[q]] - 1);
        v += TEMP_INV * posw[j] - c * __logf(d);
    }
    #pragma unroll
    for (int off = 32; off; off >>= 1) v += __shfl_xor(v, off, 64);
    if ((tid & 63) == 0) red[tid >> 6] = v;
    __syncthreads();
    if (tid == 0) {
        float s = 0.0f;
        #pragma unroll
        for (int i = 0; i < 16; ++i) s += red[i];
        out[0] = -s * (1.0f / 4096.0f);
    }
}

extern "C" void kernel_launch(void* const* d_in, const int* in_sizes, int n_in,
                              void* d_out, int out_size, void* d_ws, size_t ws_size,
                              hipStream_t stream) {
    const float* pred = (const float*)d_in[0];
    const int*   tgt  = (const int*)d_in[1];
    float* out = (float*)d_out;

    unsigned char* xn = (unsigned char*)d_ws;                        // 4 MB fp8
    float* posw = (float*)((char*)d_ws + (size_t)NROWS * DIM);
    float* denw = posw + NROWS;

    normalize_k<<<NROWS, 256, 0, stream>>>(pred, xn, posw, denw);

    fused_gram<<<(NROWS / BTM) * (NROWS / BTN), 512, 0, stream>>>(xn, tgt, posw, denw);

    finalize_k<<<1, 1024, 0, stream>>>(posw, denw, tgt, out);
}